// Round 11
// baseline (225.416 us; speedup 1.0000x reference)
//
#include <hip/hip_runtime.h>
#include <hip/hip_cooperative_groups.h>
#include <math.h>

namespace cg = cooperative_groups;

// Problem constants (B=2, N=M=2048, d_model=1024, m_bits=32, d_head=64)
#define DM 1024
#define NB 2048
#define MBITS 32
#define DH 64

typedef __attribute__((ext_vector_type(4))) float floatx4;
typedef __attribute__((ext_vector_type(8))) short shortx8;

__device__ __forceinline__ unsigned short f32_to_bf16(float f) {
    union { float f; unsigned u; } v; v.f = f;
    unsigned r = v.u + 0x7FFF + ((v.u >> 16) & 1);   // RNE
    return (unsigned short)(r >> 16);
}

// hi/lo truncation split of two f32 -> packed bf16x2 (el0 low, el1 high)
__device__ __forceinline__ void split2(float x0, float x1, unsigned& hp, unsigned& lp) {
    union { float f; unsigned u; } a, b; a.f = x0; b.f = x1;
    unsigned h0 = a.u & 0xFFFF0000u, h1 = b.u & 0xFFFF0000u;
    union { unsigned u; float f; } hf0, hf1; hf0.u = h0; hf1.u = h1;
    union { float f; unsigned u; } c, d;
    c.f = x0 - hf0.f;   // exact (Sterbenz)
    d.f = x1 - hf1.f;
    hp = (h0 >> 16) | h1;
    lp = (c.u >> 16) | (d.u & 0xFFFF0000u);
}

// ---------------------------------------------------------------------------
// Mono-kernel (r11): wprep + proj + fused in ONE cooperative dispatch.
// Grid 256 x 1024 (16 waves), 1 block/CU (co-resident by construction:
// 66 KB LDS, waves_per_eu(4,4) -> 128-reg cap -> 16 waves/CU).
//   stage 0: wprep (blocks 0-63, waves 0-3)           [body verified r3]
//   grid.sync()
//   stage 1a: proj job0 (waves 0-7) || job1 (waves 8-15), tile = blockIdx
//   stage 1b: proj job2 (waves 0-7)                    [body verified r8]
//   grid.sync()
//   stage 2: fused score+softmax+attn+PV, b=bi>>7, i0=(bi&127)*16
//                                                      [body verified r10]
// LDS: red[16][64][16] f32 (64 KB, stages 1a/1b) aliases Elds[16][2056]
// bf16 (65.8 KB, stage 2) — sequential use, separated by barriers.
// Rationale: r10 accounting leaves ~66us of unmeasured wprep+proj+gap
// residue hidden below the 41us harness fills; consolidation removes 2
// launches AND surfaces the whole pipeline as one measurable dispatch.
// ---------------------------------------------------------------------------
__global__ __attribute__((amdgpu_waves_per_eu(4, 4))) __launch_bounds__(1024)
void mono_kernel(
    const float* __restrict__ Q, const float* __restrict__ K, const float* __restrict__ V,
    const float* __restrict__ Wq, const float* __restrict__ Wk, const float* __restrict__ Wv,
    const float* __restrict__ temp, unsigned short* __restrict__ Wf,
    float* __restrict__ Qt, float* __restrict__ KtT, unsigned short* __restrict__ VpT,
    float* __restrict__ outp, float* __restrict__ attn)
{
    __shared__ __align__(16) char smem[65792];   // max(red 65536, Elds 65792)
    __shared__ float redsum[16][8];              // persists stage2 ph1 -> ph2

    float (*red)[64][16]       = (float (*)[64][16])smem;          // [16][64][16]
    unsigned short (*Elds)[2056] = (unsigned short (*)[2056])smem; // [16][2056]

    cg::grid_group grid = cg::this_grid();

    const int bi = blockIdx.x;
    const int t  = threadIdx.x;
    const int w  = t >> 6, l = t & 63;
    const int lrow = l & 15, lq = l >> 4;

    // ================= stage 0: wprep (blocks 0-63, waves 0-3) ============
    if (bi < 64 && w < 4) {
        int wv = bi * 4 + w;
        const float* W; int C, kc32, ct;
        if (wv < 64)       { W = Wq; C = 32; kc32 = wv >> 1;  ct = wv & 1; }
        else if (wv < 128) { W = Wk; C = 32; int z = wv - 64;  kc32 = z >> 1; ct = z & 1; }
        else               { W = Wv; C = 64; int z = wv - 128; kc32 = z >> 2; ct = z & 3; }
        int k0 = kc32 * 32 + lq * 8;
        int c  = ct * 16 + lrow;
        float x[8];
        #pragma unroll
        for (int j = 0; j < 8; ++j) x[j] = W[(size_t)(k0 + j) * C + c];
        unsigned hp[4], lp[4];
        #pragma unroll
        for (int j2 = 0; j2 < 4; ++j2) split2(x[2 * j2], x[2 * j2 + 1], hp[j2], lp[j2]);
        uint4 hv; hv.x = hp[0]; hv.y = hp[1]; hv.z = hp[2]; hv.w = hp[3];
        uint4 lv; lv.x = lp[0]; lv.y = lp[1]; lv.z = lp[2]; lv.w = lp[3];
        *(uint4*)&Wf[(size_t)wv * 1024 + l * 8]       = hv;
        *(uint4*)&Wf[(size_t)wv * 1024 + 512 + l * 8] = lv;
    }
    grid.sync();

    // ================= stage 1a: proj job0 (w 0-7) || job1 (w 8-15) =======
    const int r0 = bi * 16;
    {
        const int job = w >> 3;          // 0 or 1
        const int jw  = w & 7;           // wave within job
        const float* X = job ? K : Q;
        const int pbase = job << 6;

        const float* xrow = &X[(size_t)(r0 + lrow) * DM + jw * 128 + lq * 8];

        floatx4 acc[2];
        acc[0] = (floatx4){0.f, 0.f, 0.f, 0.f};
        acc[1] = (floatx4){0.f, 0.f, 0.f, 0.f};

        #pragma unroll
        for (int s = 0; s < 4; ++s) {
            floatx4 g0 = *(const floatx4*)(xrow + s * 32);
            floatx4 g1 = *(const floatx4*)(xrow + s * 32 + 4);
            union { unsigned u[4]; shortx8 v; } ahi, alo;
            split2(g0.x, g0.y, ahi.u[0], alo.u[0]);
            split2(g0.z, g0.w, ahi.u[1], alo.u[1]);
            split2(g1.x, g1.y, ahi.u[2], alo.u[2]);
            split2(g1.z, g1.w, ahi.u[3], alo.u[3]);
            int kc32 = jw * 4 + s;
            #pragma unroll
            for (int ct = 0; ct < 2; ++ct) {
                int p = pbase + kc32 * 2 + ct;
                const unsigned short* wp = &Wf[(size_t)p * 1024 + l * 8];
                shortx8 bhi = *(const shortx8*)wp;
                shortx8 blo = *(const shortx8*)(wp + 512);
                acc[ct] = __builtin_amdgcn_mfma_f32_16x16x32_bf16(ahi.v, bhi, acc[ct], 0, 0, 0);
                acc[ct] = __builtin_amdgcn_mfma_f32_16x16x32_bf16(ahi.v, blo, acc[ct], 0, 0, 0);
                acc[ct] = __builtin_amdgcn_mfma_f32_16x16x32_bf16(alo.v, bhi, acc[ct], 0, 0, 0);
            }
        }
        #pragma unroll
        for (int ct = 0; ct < 2; ++ct)
            #pragma unroll
            for (int r = 0; r < 4; ++r) red[w][l][ct * 4 + r] = acc[ct][r];
    }
    __syncthreads();
    {
        const int job = w >> 3, jw = w & 7;
        const int rr = jw & 3, ct0 = jw >> 2;     // ct0 in 0..1
        const int base = job * 8;
        int row = r0 + lq * 4 + rr;
        float v = 0.f;
        #pragma unroll
        for (int u = 0; u < 8; ++u) v += red[base + u][l][ct0 * 4 + rr];
        if (job == 0) {
            Qt[(size_t)row * MBITS + ct0 * 16 + lrow] = v;
        } else {
            int bb = row >> 11, j = row & 2047;
            KtT[(size_t)bb * (MBITS * NB) + (size_t)(ct0 * 16 + lrow) * NB + j] = v;
        }
    }
    __syncthreads();

    // ================= stage 1b: proj job2 (waves 0-7) ====================
    if (w < 8) {
        const float* xrow = &V[(size_t)(r0 + lrow) * DM + w * 128 + lq * 8];
        floatx4 acc[4];
        #pragma unroll
        for (int i = 0; i < 4; ++i) acc[i] = (floatx4){0.f, 0.f, 0.f, 0.f};

        #pragma unroll
        for (int s = 0; s < 4; ++s) {
            floatx4 g0 = *(const floatx4*)(xrow + s * 32);
            floatx4 g1 = *(const floatx4*)(xrow + s * 32 + 4);
            union { unsigned u[4]; shortx8 v; } ahi, alo;
            split2(g0.x, g0.y, ahi.u[0], alo.u[0]);
            split2(g0.z, g0.w, ahi.u[1], alo.u[1]);
            split2(g1.x, g1.y, ahi.u[2], alo.u[2]);
            split2(g1.z, g1.w, ahi.u[3], alo.u[3]);
            int kc32 = w * 4 + s;
            #pragma unroll
            for (int ct = 0; ct < 4; ++ct) {
                int p = 128 + kc32 * 4 + ct;
                const unsigned short* wp = &Wf[(size_t)p * 1024 + l * 8];
                shortx8 bhi = *(const shortx8*)wp;
                shortx8 blo = *(const shortx8*)(wp + 512);
                acc[ct] = __builtin_amdgcn_mfma_f32_16x16x32_bf16(ahi.v, bhi, acc[ct], 0, 0, 0);
                acc[ct] = __builtin_amdgcn_mfma_f32_16x16x32_bf16(ahi.v, blo, acc[ct], 0, 0, 0);
                acc[ct] = __builtin_amdgcn_mfma_f32_16x16x32_bf16(alo.v, bhi, acc[ct], 0, 0, 0);
            }
        }
        #pragma unroll
        for (int ct = 0; ct < 4; ++ct)
            #pragma unroll
            for (int r = 0; r < 4; ++r) red[w][l][ct * 4 + r] = acc[ct][r];
    }
    __syncthreads();
    if (w < 8) {
        int r = w & 3, ct0 = w >> 2;
        int row = r0 + lq * 4 + r;
        int bb = row >> 11, j = row & 2047;
        #pragma unroll
        for (int cti = 0; cti < 2; ++cti) {
            int ct = ct0 + 2 * cti;
            float v = 0.f;
            #pragma unroll
            for (int u = 0; u < 8; ++u) v += red[u][l][ct * 4 + r];
            VpT[(size_t)bb * (DH * NB) + (size_t)(ct * 16 + lrow) * NB + j] = f32_to_bf16(v);
        }
    }
    grid.sync();

    // ================= stage 2: fused score+softmax+attn+PV (r10 body) ====
    const int b  = bi >> 7;
    const int i0 = (bi & 127) * 16;

    const float tv = temp[0];
    const float c2 = -(1.0f / log1pf(__expf(tv))) * 1.44269504088896340736f;

    // ---- Phase 1: tropical min-plus, 8-row x 256-j tiles, K prefetch -----
    {
        const int rg = w & 1;
        const int jc = w >> 1;
        const int j0 = jc * 256 + l * 4;

        const float* Qb = &Qt[(size_t)(b * NB + i0 + rg * 8) * MBITS];
        const float* Kb = &KtT[(size_t)b * (MBITS * NB) + j0];

        float m[8][4];
        #pragma unroll
        for (int r = 0; r < 8; ++r)
            #pragma unroll
            for (int jj = 0; jj < 4; ++jj) m[r][jj] = 1e30f;

        floatx4 kA[4], kB[4];
        #pragma unroll
        for (int k2 = 0; k2 < 4; ++k2)
            kA[k2] = *(const floatx4*)(Kb + (size_t)k2 * NB);

        #pragma unroll 1
        for (int kc = 0; kc < 4; ++kc) {
            #pragma unroll
            for (int k2 = 0; k2 < 4; ++k2)
                kB[k2] = *(const floatx4*)(Kb + (size_t)(kc * 8 + 4 + k2) * NB);
            #pragma unroll
            for (int r = 0; r < 8; ++r) {
                floatx4 q = *(const floatx4*)(Qb + r * MBITS + kc * 8);
                #pragma unroll
                for (int k2 = 0; k2 < 4; ++k2) {
                    float qq = q[k2];
                    m[r][0] = fminf(m[r][0], qq + kA[k2].x);
                    m[r][1] = fminf(m[r][1], qq + kA[k2].y);
                    m[r][2] = fminf(m[r][2], qq + kA[k2].z);
                    m[r][3] = fminf(m[r][3], qq + kA[k2].w);
                }
            }
            if (kc < 3) {
                #pragma unroll
                for (int k2 = 0; k2 < 4; ++k2)
                    kA[k2] = *(const floatx4*)(Kb + (size_t)(kc * 8 + 8 + k2) * NB);
            }
            #pragma unroll
            for (int r = 0; r < 8; ++r) {
                floatx4 q = *(const floatx4*)(Qb + r * MBITS + kc * 8 + 4);
                #pragma unroll
                for (int k2 = 0; k2 < 4; ++k2) {
                    float qq = q[k2];
                    m[r][0] = fminf(m[r][0], qq + kB[k2].x);
                    m[r][1] = fminf(m[r][1], qq + kB[k2].y);
                    m[r][2] = fminf(m[r][2], qq + kB[k2].z);
                    m[r][3] = fminf(m[r][3], qq + kB[k2].w);
                }
            }
        }

        #pragma unroll
        for (int r = 0; r < 8; ++r) {
            float e0 = exp2f(c2 * m[r][0]);
            float e1 = exp2f(c2 * m[r][1]);
            float e2 = exp2f(c2 * m[r][2]);
            float e3 = exp2f(c2 * m[r][3]);
            uint2 pk;
            pk.x = (unsigned)f32_to_bf16(e0) | ((unsigned)f32_to_bf16(e1) << 16);
            pk.y = (unsigned)f32_to_bf16(e2) | ((unsigned)f32_to_bf16(e3) << 16);
            *(uint2*)&Elds[rg * 8 + r][j0] = pk;
            float s = (e0 + e1) + (e2 + e3);
            #pragma unroll
            for (int off = 1; off < 64; off <<= 1) s += __shfl_xor(s, off, 64);
            if (l == 0) redsum[w][r] = s;
        }
    }
    __syncthreads();

    // ---- Phase 2: PV MFMA (direct global B-frags) + attn write -----------
    const int mrow = l & 15, q4 = l >> 4;
    const int hh  = (w & 3) * 16 + mrow;
    const int kg  = w >> 2;
    floatx4 acc2 = {0.f, 0.f, 0.f, 0.f};
    const unsigned short* Vb = &VpT[(size_t)b * (DH * NB) + (size_t)hh * NB];

    #pragma unroll
    for (int jc2 = 0; jc2 < 8; ++jc2) {
        #pragma unroll
        for (int t2 = 0; t2 < 2; ++t2) {
            int ks = kg * 2 + t2;
            int joff = jc2 * 256 + ks * 32 + q4 * 8;
            shortx8 a  = *(const shortx8*)&Elds[mrow][joff];
            shortx8 bf = *(const shortx8*)&Vb[joff];
            acc2 = __builtin_amdgcn_mfma_f32_16x16x32_bf16(a, bf, acc2, 0, 0, 0);
        }
    }

    {
        float s = 0.f;
        #pragma unroll
        for (int g = 0; g < 8; ++g) s += redsum[(w >> 3) + 2 * g][w & 7];
        float iv = 1.0f / s;
        #pragma unroll
        for (int u = 0; u < 8; ++u) {
            int j = u * 256 + l * 4;
            uint2 pk = *(const uint2*)&Elds[w][j];
            union { unsigned u; float f; } x0, x1, x2, x3;
            x0.u = pk.x << 16; x1.u = pk.x & 0xFFFF0000u;
            x2.u = pk.y << 16; x3.u = pk.y & 0xFFFF0000u;
            floatx4 o;
            o.x = x0.f * iv; o.y = x1.f * iv; o.z = x2.f * iv; o.w = x3.f * iv;
            *(floatx4*)&attn[(size_t)(b * NB + i0 + w) * 2048 + j] = o;
        }
    }
    __syncthreads();   // all Elds reads done -> safe to reuse as redC

    float* redCf = (float*)&Elds[0][0];   // [12][64][4] floats = 12 KB
    if (w >= 4) *(floatx4*)&redCf[(((w - 4) * 64) + l) * 4] = acc2;
    __syncthreads();
    if (w < 4) {
        floatx4 v0 = *(const floatx4*)&redCf[((w * 64) + l) * 4];
        floatx4 v1 = *(const floatx4*)&redCf[(((w + 4) * 64) + l) * 4];
        floatx4 v2 = *(const floatx4*)&redCf[(((w + 8) * 64) + l) * 4];
        #pragma unroll
        for (int r = 0; r < 4; ++r) {
            int irow = q4 * 4 + r;
            float sr = 0.f;
            #pragma unroll
            for (int g = 0; g < 8; ++g) sr += redsum[(irow >> 3) + 2 * g][irow & 7];
            float ivr = 1.0f / sr;
            float v = ((acc2[r] + v0[r]) + (v1[r] + v2[r]));
            outp[(size_t)(b * NB + i0 + irow) * DH + w * 16 + mrow] = v * ivr;
        }
    }
}

// ---------------------------------------------------------------------------
extern "C" void kernel_launch(void* const* d_in, const int* in_sizes, int n_in,
                              void* d_out, int out_size, void* d_ws, size_t ws_size,
                              hipStream_t stream) {
    (void)in_sizes; (void)n_in; (void)out_size; (void)ws_size;
    const float* Q    = (const float*)d_in[0];
    const float* K    = (const float*)d_in[1];
    const float* V    = (const float*)d_in[2];
    const float* Wq   = (const float*)d_in[3];
    const float* Wk   = (const float*)d_in[4];
    const float* Wv   = (const float*)d_in[5];
    const float* temp = (const float*)d_in[6];

    float* outp = (float*)d_out;                 // [2][2048][64]
    float* attn = outp + 2 * 2048 * 64;          // [2][2048][2048]

    char* ws = (char*)d_ws;
    float*          Qt  = (float*)(ws);                       // 512 KB
    float*          KtT = (float*)(ws + 524288);              // 512 KB  [2][32][2048]
    unsigned short* Wf  = (unsigned short*)(ws + 1179648);    // 512 KB
    unsigned short* VpT = (unsigned short*)(ws + 1703936);    // 512 KB

    void* kargs[] = {
        (void*)&Q, (void*)&K, (void*)&V, (void*)&Wq, (void*)&Wk, (void*)&Wv,
        (void*)&temp, (void*)&Wf, (void*)&Qt, (void*)&KtT, (void*)&VpT,
        (void*)&outp, (void*)&attn
    };
    hipLaunchCooperativeKernel((const void*)mono_kernel, dim3(256), dim3(1024),
                               kargs, 0, stream);
}

// Round 12
// 146.122 us; speedup vs baseline: 1.5427x; 1.5427x over previous
//
#include <hip/hip_runtime.h>
#include <math.h>

// Problem constants (B=2, N=M=2048, d_model=1024, m_bits=32, d_head=64)
#define DM 1024
#define NB 2048
#define MBITS 32
#define DH 64

typedef __attribute__((ext_vector_type(4))) float floatx4;
typedef __attribute__((ext_vector_type(8))) short shortx8;

__device__ __forceinline__ unsigned short f32_to_bf16(float f) {
    union { float f; unsigned u; } v; v.f = f;
    unsigned r = v.u + 0x7FFF + ((v.u >> 16) & 1);   // RNE
    return (unsigned short)(r >> 16);
}

// hi/lo truncation split of two f32 -> packed bf16x2 (el0 low, el1 high)
__device__ __forceinline__ void split2(float x0, float x1, unsigned& hp, unsigned& lp) {
    union { float f; unsigned u; } a, b; a.f = x0; b.f = x1;
    unsigned h0 = a.u & 0xFFFF0000u, h1 = b.u & 0xFFFF0000u;
    union { unsigned u; float f; } hf0, hf1; hf0.u = h0; hf1.u = h1;
    union { float f; unsigned u; } c, d;
    c.f = x0 - hf0.f;   // exact (Sterbenz)
    d.f = x1 - hf1.f;
    hp = (h0 >> 16) | h1;
    lp = (c.u >> 16) | (d.u & 0xFFFF0000u);
}

// ---------------------------------------------------------------------------
// Projections (r12): wprep folded in — the W B-frag pack is recomputed
// inline per page right before its MFMAs (identical lane math to the old
// wprep: page p, lane l -> k0 = kc32*32 + (l>>4)*8, c = ct*16 + (l&15),
// split2 hi/lo pairs). Kills the wprep kernel, its launch gap, and the
// 1 MB Wf global round-trip. W inputs are L1/L2-hot (re-read per block).
// Otherwise byte-identical to the verified r8 proj: 8-wave blocks (512 thr),
// split-K x8, red[8][64][16] LDS reduction, grid 768.
// Job 1 writes KtT[b][k=32][j=2048] (verified r5).
// ---------------------------------------------------------------------------
__global__ __launch_bounds__(512) void proj_kernel(
    const float* __restrict__ Q, const float* __restrict__ K, const float* __restrict__ V,
    const float* __restrict__ Wq, const float* __restrict__ Wk, const float* __restrict__ Wv,
    float* __restrict__ Qt, float* __restrict__ KtT, unsigned short* __restrict__ VpT)
{
    __shared__ float red[8][64][16];   // [wave][lane][ct*4+r]  = 32 KB

    int gb = blockIdx.x;
    int job = gb >> 8, tile = gb & 255;
    int r0 = tile * 16;
    const float* X = (job == 0) ? Q : (job == 1) ? K : V;
    const float* W = (job == 0) ? Wq : (job == 1) ? Wk : Wv;
    int C     = (job == 2) ? 64 : 32;
    int ntct  = (job == 2) ? 4 : 2;
    int t = threadIdx.x, w = t >> 6, l = t & 63;
    int lrow = l & 15, lq = l >> 4;

    const float* xrow = &X[(size_t)(r0 + lrow) * DM + w * 128 + lq * 8];

    floatx4 acc[4];
    #pragma unroll
    for (int i = 0; i < 4; ++i) acc[i] = (floatx4){0.f, 0.f, 0.f, 0.f};

    #pragma unroll
    for (int s = 0; s < 4; ++s) {
        floatx4 g0 = *(const floatx4*)(xrow + s * 32);
        floatx4 g1 = *(const floatx4*)(xrow + s * 32 + 4);
        union { unsigned u[4]; shortx8 v; } ahi, alo;
        split2(g0.x, g0.y, ahi.u[0], alo.u[0]);
        split2(g0.z, g0.w, ahi.u[1], alo.u[1]);
        split2(g1.x, g1.y, ahi.u[2], alo.u[2]);
        split2(g1.z, g1.w, ahi.u[3], alo.u[3]);
        int kc32 = w * 4 + s;
        int k0   = kc32 * 32 + lq * 8;
        #pragma unroll
        for (int ct = 0; ct < 4; ++ct) {
            if (ct >= ntct) break;
            // inline W-pack for page (kc32, ct) — identical to old wprep lane math
            int c = ct * 16 + lrow;
            float x[8];
            #pragma unroll
            for (int j = 0; j < 8; ++j) x[j] = W[(size_t)(k0 + j) * C + c];
            union { unsigned u[4]; shortx8 v; } bh, bl;
            #pragma unroll
            for (int j2 = 0; j2 < 4; ++j2) split2(x[2 * j2], x[2 * j2 + 1], bh.u[j2], bl.u[j2]);
            acc[ct] = __builtin_amdgcn_mfma_f32_16x16x32_bf16(ahi.v, bh.v, acc[ct], 0, 0, 0);
            acc[ct] = __builtin_amdgcn_mfma_f32_16x16x32_bf16(ahi.v, bl.v, acc[ct], 0, 0, 0);
            acc[ct] = __builtin_amdgcn_mfma_f32_16x16x32_bf16(alo.v, bh.v, acc[ct], 0, 0, 0);
        }
    }

    #pragma unroll
    for (int ct = 0; ct < 4; ++ct) {
        if (ct >= ntct) break;
        #pragma unroll
        for (int r = 0; r < 4; ++r) red[w][l][ct * 4 + r] = acc[ct][r];
    }
    __syncthreads();

    int r = w & 3, ct0 = w >> 2;
    int row = r0 + lq * 4 + r;
    if (job == 0) {
        float v = red[0][l][ct0 * 4 + r] + red[1][l][ct0 * 4 + r]
                + red[2][l][ct0 * 4 + r] + red[3][l][ct0 * 4 + r]
                + red[4][l][ct0 * 4 + r] + red[5][l][ct0 * 4 + r]
                + red[6][l][ct0 * 4 + r] + red[7][l][ct0 * 4 + r];
        Qt[(size_t)row * MBITS + ct0 * 16 + lrow] = v;
    } else if (job == 1) {
        int bb = row >> 11, j = row & 2047;
        float v = red[0][l][ct0 * 4 + r] + red[1][l][ct0 * 4 + r]
                + red[2][l][ct0 * 4 + r] + red[3][l][ct0 * 4 + r]
                + red[4][l][ct0 * 4 + r] + red[5][l][ct0 * 4 + r]
                + red[6][l][ct0 * 4 + r] + red[7][l][ct0 * 4 + r];
        KtT[(size_t)bb * (MBITS * NB) + (size_t)(ct0 * 16 + lrow) * NB + j] = v;
    } else {
        int bb = row >> 11, j = row & 2047;
        #pragma unroll
        for (int cti = 0; cti < 2; ++cti) {
            int ct = ct0 + 2 * cti;
            float v = red[0][l][ct * 4 + r] + red[1][l][ct * 4 + r]
                    + red[2][l][ct * 4 + r] + red[3][l][ct * 4 + r]
                    + red[4][l][ct * 4 + r] + red[5][l][ct * 4 + r]
                    + red[6][l][ct * 4 + r] + red[7][l][ct * 4 + r];
            VpT[(size_t)bb * (DH * NB) + (size_t)(ct * 16 + lrow) * NB + j] = f32_to_bf16(v);
        }
    }
}

// ---------------------------------------------------------------------------
// Fused score + softmax + attn-write + PV pass.  (r10 body, UNCHANGED —
// verified at ~36us steady state; kept bitwise-identical so the total delta
// this round cleanly attributes to the wprep merge + launch-count change.)
// ---------------------------------------------------------------------------
__global__ __attribute__((amdgpu_waves_per_eu(4, 4))) __launch_bounds__(1024)
void fused_score_out_kernel(
    const float* __restrict__ Qt, const float* __restrict__ KtT,
    const unsigned short* __restrict__ VpT, const float* __restrict__ temp,
    float* __restrict__ outp, float* __restrict__ attn)
{
    __shared__ unsigned short Elds[16][2056];    // 65792 B  unnormalized e (bf16)
    __shared__ float redsum[16][8];              //   512 B  [wave][local row]

    const int b  = blockIdx.y;
    const int i0 = blockIdx.x * 16;
    const int t  = threadIdx.x;
    const int w  = t >> 6, l = t & 63;

    const float tv = temp[0];
    const float c2 = -(1.0f / log1pf(__expf(tv))) * 1.44269504088896340736f;

    // ---- Phase 1: tropical min-plus, 8-row x 256-j tiles, K prefetch -----
    {
        const int rg = w & 1;            // row-group: rows rg*8 .. rg*8+7
        const int jc = w >> 1;           // j-chunk (256 j)
        const int j0 = jc * 256 + l * 4; // this lane's 4 consecutive j

        const float* Qb = &Qt[(size_t)(b * NB + i0 + rg * 8) * MBITS];
        const float* Kb = &KtT[(size_t)b * (MBITS * NB) + j0];

        float m[8][4];
        #pragma unroll
        for (int r = 0; r < 8; ++r)
            #pragma unroll
            for (int jj = 0; jj < 4; ++jj) m[r][jj] = 1e30f;

        floatx4 kA[4], kB[4];
        #pragma unroll
        for (int k2 = 0; k2 < 4; ++k2)
            kA[k2] = *(const floatx4*)(Kb + (size_t)k2 * NB);

        #pragma unroll 1
        for (int kc = 0; kc < 4; ++kc) {
            #pragma unroll
            for (int k2 = 0; k2 < 4; ++k2)
                kB[k2] = *(const floatx4*)(Kb + (size_t)(kc * 8 + 4 + k2) * NB);
            #pragma unroll
            for (int r = 0; r < 8; ++r) {
                floatx4 q = *(const floatx4*)(Qb + r * MBITS + kc * 8);
                #pragma unroll
                for (int k2 = 0; k2 < 4; ++k2) {
                    float qq = q[k2];
                    m[r][0] = fminf(m[r][0], qq + kA[k2].x);
                    m[r][1] = fminf(m[r][1], qq + kA[k2].y);
                    m[r][2] = fminf(m[r][2], qq + kA[k2].z);
                    m[r][3] = fminf(m[r][3], qq + kA[k2].w);
                }
            }
            if (kc < 3) {
                #pragma unroll
                for (int k2 = 0; k2 < 4; ++k2)
                    kA[k2] = *(const floatx4*)(Kb + (size_t)(kc * 8 + 8 + k2) * NB);
            }
            #pragma unroll
            for (int r = 0; r < 8; ++r) {
                floatx4 q = *(const floatx4*)(Qb + r * MBITS + kc * 8 + 4);
                #pragma unroll
                for (int k2 = 0; k2 < 4; ++k2) {
                    float qq = q[k2];
                    m[r][0] = fminf(m[r][0], qq + kB[k2].x);
                    m[r][1] = fminf(m[r][1], qq + kB[k2].y);
                    m[r][2] = fminf(m[r][2], qq + kB[k2].z);
                    m[r][3] = fminf(m[r][3], qq + kB[k2].w);
                }
            }
        }

        // e = exp2(c2*m); pack bf16 -> Elds; per-row 256-j sums -> redsum
        #pragma unroll
        for (int r = 0; r < 8; ++r) {
            float e0 = exp2f(c2 * m[r][0]);
            float e1 = exp2f(c2 * m[r][1]);
            float e2 = exp2f(c2 * m[r][2]);
            float e3 = exp2f(c2 * m[r][3]);
            uint2 pk;
            pk.x = (unsigned)f32_to_bf16(e0) | ((unsigned)f32_to_bf16(e1) << 16);
            pk.y = (unsigned)f32_to_bf16(e2) | ((unsigned)f32_to_bf16(e3) << 16);
            *(uint2*)&Elds[rg * 8 + r][j0] = pk;
            float s = (e0 + e1) + (e2 + e3);
            #pragma unroll
            for (int off = 1; off < 64; off <<= 1) s += __shfl_xor(s, off, 64);
            if (l == 0) redsum[w][r] = s;
        }
    }
    __syncthreads();

    // ---- Phase 2: PV MFMA (direct global B-frags, verified r6-r10) -------
    const int mrow = l & 15, q4 = l >> 4;
    const int hh  = (w & 3) * 16 + mrow;   // output head column this wave owns
    const int kg  = w >> 2;                // k-split group (0..3)
    floatx4 acc = {0.f, 0.f, 0.f, 0.f};
    const unsigned short* Vb = &VpT[(size_t)b * (DH * NB) + (size_t)hh * NB];

    #pragma unroll
    for (int jc2 = 0; jc2 < 8; ++jc2) {
        #pragma unroll
        for (int t2 = 0; t2 < 2; ++t2) {
            int ks = kg * 2 + t2;
            int joff = jc2 * 256 + ks * 32 + q4 * 8;
            shortx8 a  = *(const shortx8*)&Elds[mrow][joff];
            shortx8 bf = *(const shortx8*)&Vb[joff];
            acc = __builtin_amdgcn_mfma_f32_16x16x32_bf16(a, bf, acc, 0, 0, 0);
        }
    }

    // attn write: wave w owns row w; 8 x 1KB coalesced chunks.
    // row i total = sum over g of redsum[(i>>3) + 2g][i&7]
    {
        float s = 0.f;
        #pragma unroll
        for (int g = 0; g < 8; ++g) s += redsum[(w >> 3) + 2 * g][w & 7];
        float iv = 1.0f / s;
        #pragma unroll
        for (int u = 0; u < 8; ++u) {
            int j = u * 256 + l * 4;
            uint2 pk = *(const uint2*)&Elds[w][j];
            union { unsigned u; float f; } x0, x1, x2, x3;
            x0.u = pk.x << 16; x1.u = pk.x & 0xFFFF0000u;
            x2.u = pk.y << 16; x3.u = pk.y & 0xFFFF0000u;
            floatx4 o;
            o.x = x0.f * iv; o.y = x1.f * iv; o.z = x2.f * iv; o.w = x3.f * iv;
            *(floatx4*)&attn[(size_t)(b * NB + i0 + w) * 2048 + j] = o;
        }
    }
    __syncthreads();   // all Elds reads done -> safe to reuse as redC

    // cross-wave reduce the 4 k-split partials; redC aliases Elds
    float* redCf = (float*)&Elds[0][0];   // [12][64][4] floats = 12 KB
    if (w >= 4) *(floatx4*)&redCf[(((w - 4) * 64) + l) * 4] = acc;
    __syncthreads();
    if (w < 4) {
        floatx4 v0 = *(const floatx4*)&redCf[((w * 64) + l) * 4];
        floatx4 v1 = *(const floatx4*)&redCf[(((w + 4) * 64) + l) * 4];
        floatx4 v2 = *(const floatx4*)&redCf[(((w + 8) * 64) + l) * 4];
        #pragma unroll
        for (int r = 0; r < 4; ++r) {
            int irow = q4 * 4 + r;
            float sr = 0.f;
            #pragma unroll
            for (int g = 0; g < 8; ++g) sr += redsum[(irow >> 3) + 2 * g][irow & 7];
            float ivr = 1.0f / sr;
            float v = ((acc[r] + v0[r]) + (v1[r] + v2[r]));
            outp[(size_t)(b * NB + i0 + irow) * DH + w * 16 + mrow] = v * ivr;
        }
    }
}

// ---------------------------------------------------------------------------
extern "C" void kernel_launch(void* const* d_in, const int* in_sizes, int n_in,
                              void* d_out, int out_size, void* d_ws, size_t ws_size,
                              hipStream_t stream) {
    (void)in_sizes; (void)n_in; (void)out_size; (void)ws_size;
    const float* Q    = (const float*)d_in[0];
    const float* K    = (const float*)d_in[1];
    const float* V    = (const float*)d_in[2];
    const float* Wq   = (const float*)d_in[3];
    const float* Wk   = (const float*)d_in[4];
    const float* Wv   = (const float*)d_in[5];
    const float* temp = (const float*)d_in[6];

    float* outp = (float*)d_out;                 // [2][2048][64]
    float* attn = outp + 2 * 2048 * 64;          // [2][2048][2048]

    char* ws = (char*)d_ws;
    float*          Qt  = (float*)(ws);                       // 512 KB
    float*          KtT = (float*)(ws + 524288);              // 512 KB  [2][32][2048]
    unsigned short* VpT = (unsigned short*)(ws + 1703936);    // 512 KB

    proj_kernel<<<768, 512, 0, stream>>>(Q, K, V, Wq, Wk, Wv, Qt, KtT, VpT);
    fused_score_out_kernel<<<dim3(128, 2), 1024, 0, stream>>>(Qt, KtT, VpT, temp, outp, attn);
}